// Round 5
// baseline (46259.833 us; speedup 1.0000x reference)
//
#include <hip/hip_runtime.h>
#include <stdint.h>

// ----------------------------------------------------------------------------
// 2-layer LSTM (T=8192, IN=9, H=1024) + Linear(H->1), fp32, single cooperative
// kernel, 256 blocks x 1024 threads (16 waves), 1 block/CU.
//
// Round-2 post-mortem: L1 waves needed ~180 VGPR; compiler capped at 128 and
// spilled 4KB/thread (WRITE_SIZE was exactly 512MB) -> scan was L2-BW-bound on
// spill reloads. THIS version removes the >128 requirement structurally:
// GATE-SPLIT. Each hidden unit's 4 gates are split across 2 waves:
//   p=0 wave: gates {i,f};  p=1 wave: gates {g,o}.
// Per-wave weights: L1 = 16 float4 (64 VGPR), L0 = 8 float4 + wxr[2][9].
// Everything fits the default 128-VGPR budget of __launch_bounds__(1024).
//
// Block b owns units 4b..4b+3 of BOTH layers:
//   wv 0..7  -> layer 0, unit 4b+(wv>>1), pair wv&1
//   wv 8..15 -> layer 1, unit 4b+((wv>>1)&3), pair wv&1
// (wave->SIMD = wv&3: each SIMD gets 2 L0 + 2 L1 waves -> balanced.)
//
// Round r: L0 computes step r (r<T), L1 computes step r-1 (r>=1).
// Cross-wave combine: p=1 wave writes activated {g,o} to LDS; p=0 wave (owner
// of cell state c) reads them after the second barrier, updates c, publishes h.
//
// Communication: value-carrying mailboxes pub[slot][unit] = u64{seq|h},
// relaxed agent-scope 8B atomics, ring depth 4 (all blocks provably within one
// round of each other; seq check + append-only-within-slot-window => race-free;
// 0xAA ws poison = "empty", no ws init needed).
//
// LDS bank conflicts (1.34e8 in round 2): ds_read_b128 at 16B/lane stride is an
// 8-way alias. Fix: XOR-swizzle the float4 index (q ^= (q>>3)&7, involution),
// applied at h-stage write and at fragment read -> every 8-lane cluster covers
// all 8 bank quads.
// ----------------------------------------------------------------------------

#define TSTEPS 8192
#define HDIM   1024
#define BS     1024
#define NBLK   256
#define RINGM  3        // ring depth 4

typedef unsigned long long u64;
typedef unsigned int u32;

__device__ __forceinline__ float sigm(float x)  { return 1.0f / (1.0f + __expf(-x)); }
__device__ __forceinline__ float tanh_(float x) { return 1.0f - 2.0f / (__expf(2.0f * x) + 1.0f); }
__device__ __forceinline__ float dot4(float4 a, float4 b) {
  return a.x * b.x + a.y * b.y + a.z * b.z + a.w * b.w;
}
__device__ __forceinline__ void pin4(float4& v) {
  asm volatile("" : "+v"(v.x), "+v"(v.y), "+v"(v.z), "+v"(v.w));
}

// Spin until slot's seq field == want; returns the word (value in lo32).
__device__ __forceinline__ u64 pollslot(const u64* p, u32 want) {
  u64 v = __hip_atomic_load(p, __ATOMIC_RELAXED, __HIP_MEMORY_SCOPE_AGENT);
  while ((u32)(v >> 32) != want) {
    __builtin_amdgcn_s_sleep(1);
    v = __hip_atomic_load(p, __ATOMIC_RELAXED, __HIP_MEMORY_SCOPE_AGENT);
  }
  return v;
}

__device__ __forceinline__ void publish(u64* p, u32 seq, float h) {
  u64 v = ((u64)seq << 32) | (u64)__float_as_uint(h);
  __hip_atomic_store(p, v, __ATOMIC_RELAXED, __HIP_MEMORY_SCOPE_AGENT);
}

__global__ void __launch_bounds__(BS) lstm_fused(
    const float* __restrict__ xin,   // [T][9]
    const float* __restrict__ wih0,  // [4H][9]
    const float* __restrict__ whh0,  // [4H][H]
    const float* __restrict__ bih0, const float* __restrict__ bhh0,
    const float* __restrict__ wih1,  // [4H][H]
    const float* __restrict__ whh1,  // [4H][H]
    const float* __restrict__ bih1, const float* __restrict__ bhh1,
    const float* __restrict__ wlin, const float* __restrict__ blin,
    float* __restrict__ out,
    u64* __restrict__ pub1, u64* __restrict__ pub2)   // [4][HDIM] each
{
  const int b   = blockIdx.x;
  const int tid = threadIdx.x;
  const int wv  = tid >> 6;
  const int ln  = tid & 63;
  const int layer = wv >> 3;               // 0 or 1
  const int ul    = (wv >> 1) & 3;         // unit-local 0..3
  const int p     = wv & 1;                // gate pair: 0->{i,f}, 1->{g,o}
  const int unit  = 4 * b + ul;
  const int g0    = 2 * p;                 // first gate of this pair

  __shared__ __align__(16) float hA[HDIM]; // h1 for this round
  __shared__ __align__(16) float hB[HDIM]; // h2 for this round
  __shared__ float glds[2][4][2];          // [layer][ul][{g,o}]
  __shared__ float red16[16];

  // ---- weights -> registers (pinned; all fit under 128 VGPR) -------------
  // lane ln holds logical float4 k-chunks q = ln + 64*j (j=0..3) of each row.
  float4 wrr[2][4];                        // recurrent rows (whh0 / whh1)
  {
    const float* WR = layer ? whh1 : whh0;
    #pragma unroll
    for (int gi = 0; gi < 2; ++gi)
      #pragma unroll
      for (int j = 0; j < 4; ++j) {
        wrr[gi][j] = *reinterpret_cast<const float4*>(
            WR + (size_t)((g0 + gi) * HDIM + unit) * HDIM + 4 * ln + 256 * j);
        pin4(wrr[gi][j]);
      }
  }
  float4 wii[2][4];                        // layer-1 only: w_ih1 rows
  if (layer) {
    #pragma unroll
    for (int gi = 0; gi < 2; ++gi)
      #pragma unroll
      for (int j = 0; j < 4; ++j) {
        wii[gi][j] = *reinterpret_cast<const float4*>(
            wih1 + (size_t)((g0 + gi) * HDIM + unit) * HDIM + 4 * ln + 256 * j);
        pin4(wii[gi][j]);
      }
  }
  float wxr[2][9];                         // layer-0 only: w_ih0 rows
  if (!layer) {
    #pragma unroll
    for (int gi = 0; gi < 2; ++gi) {
      #pragma unroll
      for (int k = 0; k < 9; ++k)
        wxr[gi][k] = wih0[(size_t)((g0 + gi) * HDIM + unit) * 9 + k];
      asm volatile("" : "+v"(wxr[gi][0]), "+v"(wxr[gi][1]), "+v"(wxr[gi][2]),
                        "+v"(wxr[gi][3]), "+v"(wxr[gi][4]), "+v"(wxr[gi][5]),
                        "+v"(wxr[gi][6]), "+v"(wxr[gi][7]), "+v"(wxr[gi][8]));
    }
  }
  float bias[2];
  #pragma unroll
  for (int gi = 0; gi < 2; ++gi)
    bias[gi] = layer ? (bih1[(g0 + gi) * HDIM + unit] + bhh1[(g0 + gi) * HDIM + unit])
                     : (bih0[(g0 + gi) * HDIM + unit] + bhh0[(g0 + gi) * HDIM + unit]);
  asm volatile("" : "+v"(bias[0]), "+v"(bias[1]));

  float c = 0.0f;                          // cell state (lives in p==0 waves)

  // Swizzle: float4 slot s holds logical chunk SW(s), SW(q)=q^((q>>3)&7).
  const int q4   = tid >> 2, lo4 = tid & 3;
  const int sidx = 4 * (q4 ^ ((q4 >> 3) & 7)) + lo4;  // staging scalar index
  const int lnx  = ln ^ (ln >> 3);                    // read base (j-invariant)
  const float4* hA4 = reinterpret_cast<const float4*>(hA);
  const float4* hB4 = reinterpret_cast<const float4*>(hB);

  // ======================== round loop ====================================
  for (int r = 0; r <= TSTEPS; ++r) {
    float xr[9];
    if (!layer && r < TSTEPS) {
      #pragma unroll
      for (int k = 0; k < 9; ++k) xr[k] = xin[r * 9 + k];
    }

    // ---- poll/stage: thread tid owns element tid of hA and hB -----------
    if (r >= 1) {                          // h1[r-1], seq r
      u64 v = pollslot(pub1 + ((size_t)((r - 1) & RINGM) << 10) + tid, (u32)r);
      hA[sidx] = __uint_as_float((u32)v);
    } else {
      hA[sidx] = 0.0f;
    }
    if (r >= 2) {                          // h2[r-2], seq r-1
      u64 v = pollslot(pub2 + ((size_t)((r - 2) & RINGM) << 10) + tid, (u32)(r - 1));
      hB[sidx] = __uint_as_float((u32)v);
    } else if (r == 0) {
      hB[sidx] = 0.0f;                     // stays zero through r==1
    }
    __syncthreads();

    // ---- dot phase ------------------------------------------------------
    const bool active = layer ? (r >= 1) : (r < TSTEPS);
    float iv = 0.0f, fv = 0.0f;
    if (active) {
      float a0 = 0.0f, a1 = 0.0f;
      if (!layer) {
        #pragma unroll
        for (int j = 0; j < 4; ++j) {
          float4 h4 = hA4[lnx + (j << 6)];
          a0 += dot4(wrr[0][j], h4); a1 += dot4(wrr[1][j], h4);
        }
      } else {
        #pragma unroll
        for (int j = 0; j < 4; ++j) {
          float4 ha = hA4[lnx + (j << 6)];
          float4 hb = hB4[lnx + (j << 6)];
          a0 += dot4(wii[0][j], ha) + dot4(wrr[0][j], hb);
          a1 += dot4(wii[1][j], ha) + dot4(wrr[1][j], hb);
        }
      }
      #pragma unroll
      for (int d = 1; d < 64; d <<= 1) {
        a0 += __shfl_xor(a0, d); a1 += __shfl_xor(a1, d);
      }
      a0 += bias[0]; a1 += bias[1];
      if (!layer) {
        #pragma unroll
        for (int k = 0; k < 9; ++k) { a0 += wxr[0][k] * xr[k]; a1 += wxr[1][k] * xr[k]; }
      }
      if (p == 0) {                        // gates i, f — keep in registers
        iv = sigm(a0); fv = sigm(a1);
      } else {                             // gates g, o — hand to p==0 wave
        float gg = tanh_(a0), ov = sigm(a1);
        if (ln == 0) { glds[layer][ul][0] = gg; glds[layer][ul][1] = ov; }
      }
    }
    __syncthreads();

    // ---- combine + publish (p==0 waves own c) ---------------------------
    if (active && p == 0) {
      float gg = glds[layer][ul][0];
      float ov = glds[layer][ul][1];
      c = fv * c + iv * gg;
      float h = ov * tanh_(c);
      if (ln == 0) {
        if (!layer)
          publish(pub1 + ((size_t)(r & RINGM) << 10) + unit, (u32)(r + 1), h);
        else
          publish(pub2 + ((size_t)((r - 1) & RINGM) << 10) + unit, (u32)r, h);
      }
    }
  }

  // ---- final Linear(h2[T-1]) by block 0 ----------------------------------
  if (b == 0) {
    u64 v = pollslot(pub2 + ((size_t)((TSTEPS - 1) & RINGM) << 10) + tid,
                     (u32)TSTEPS);
    float pp = __uint_as_float((u32)v) * wlin[tid];
    #pragma unroll
    for (int d = 1; d < 64; d <<= 1) pp += __shfl_xor(pp, d);
    if (ln == 0) red16[wv] = pp;
    __syncthreads();
    if (tid == 0) {
      float s = blin[0];
      #pragma unroll
      for (int w = 0; w < 16; ++w) s += red16[w];
      out[0] = s;
    }
  }
}

extern "C" void kernel_launch(void* const* d_in, const int* in_sizes, int n_in,
                              void* d_out, int out_size, void* d_ws, size_t ws_size,
                              hipStream_t stream)
{
  const float* xin  = (const float*)d_in[0];
  const float* wih0 = (const float*)d_in[1];
  const float* whh0 = (const float*)d_in[2];
  const float* bih0 = (const float*)d_in[3];
  const float* bhh0 = (const float*)d_in[4];
  const float* wih1 = (const float*)d_in[5];
  const float* whh1 = (const float*)d_in[6];
  const float* bih1 = (const float*)d_in[7];
  const float* bhh1 = (const float*)d_in[8];
  const float* wlin = (const float*)d_in[9];
  const float* blin = (const float*)d_in[10];
  float* out = (float*)d_out;

  // Ring mailboxes in ws: pub1[4][1024] u64, pub2[4][1024] u64 = 64 KB total.
  // 0xAA poison is the "empty" marker (seq 0xAAAAAAAA never valid).
  u64* pub1 = (u64*)d_ws;
  u64* pub2 = pub1 + 4 * HDIM;

  void* args[] = { &xin, &wih0, &whh0, &bih0, &bhh0,
                   &wih1, &whh1, &bih1, &bhh1, &wlin, &blin,
                   &out, &pub1, &pub2 };
  hipLaunchCooperativeKernel(reinterpret_cast<void*>(&lstm_fused),
                             dim3(NBLK), dim3(BS), args, 0, stream);
}

// Round 6
// 19376.460 us; speedup vs baseline: 2.3874x; 2.3874x over previous
//
#include <hip/hip_runtime.h>
#include <stdint.h>

// ----------------------------------------------------------------------------
// 2-layer LSTM (T=8192, IN=9, H=1024) + Linear(H->1), fp32, single cooperative
// kernel, 256 blocks x 512 threads (1 block/CU guaranteed co-resident).
//
// Round-2 post-mortem: compiler capped VGPR at 128 (needs ~180 for L1 waves'
// weights), spilling 4KB/thread to scratch (WRITE_SIZE was exactly 512MB) and
// reloading per round from L2 -> the scan was L2-BW-bound on spill reloads.
// Round-5 confirmed from the other side: without waves_per_eu the allocator
// targeted 8 waves/EU (64 VGPR!) and spilled again (46ms). Fix here:
// amdgpu_waves_per_eu(2,2) pins the budget at 256 VGPRs, and every weight
// register is pinned with an empty asm so LLVM can't remat/sink the loads.
//
// Decomposition: block b owns hidden units 4b..4b+3 of BOTH layers.
//   waves 0..3  -> layer-0 unit (4b+wv)
//   waves 4..7  -> layer-1 unit (4b+wv-4)
// Communication: value-carrying mailboxes pub[slot][unit] = u64{seq|h},
// relaxed agent-scope 8B atomics (self-synchronizing, 1 LLC trip each way).
// Ring depth 4; blocks provably within 2 rounds of each other (each round
// consumes ALL units' previous-round publishes), so slot reuse at distance 4
// is race-free. 0xAA ws poison = "empty" (seq 0xAAAAAAAA never valid), so no
// ws init needed.
// ----------------------------------------------------------------------------

#define TSTEPS 8192
#define HDIM   1024
#define BS     512
#define NBLK   256
#define RINGM  3        // ring mask (depth 4)

typedef unsigned long long u64;
typedef unsigned int u32;

__device__ __forceinline__ float sigm(float x)  { return 1.0f / (1.0f + __expf(-x)); }
__device__ __forceinline__ float tanh_(float x) { return 1.0f - 2.0f / (__expf(2.0f * x) + 1.0f); }
__device__ __forceinline__ float dot4(float4 a, float4 b) {
  return a.x * b.x + a.y * b.y + a.z * b.z + a.w * b.w;
}
// Pin a float4 into VGPRs: value becomes opaque (no remat, no sinking).
__device__ __forceinline__ void pin4(float4& v) {
  asm volatile("" : "+v"(v.x), "+v"(v.y), "+v"(v.z), "+v"(v.w));
}

// Spin until slot's seq field == want; returns the full word (value in lo32).
__device__ __forceinline__ u64 pollslot(const u64* p, u32 want) {
  u64 v = __hip_atomic_load(p, __ATOMIC_RELAXED, __HIP_MEMORY_SCOPE_AGENT);
  while ((u32)(v >> 32) != want) {
    __builtin_amdgcn_s_sleep(1);
    v = __hip_atomic_load(p, __ATOMIC_RELAXED, __HIP_MEMORY_SCOPE_AGENT);
  }
  return v;
}

__device__ __forceinline__ void publish(u64* p, u32 seq, float h) {
  u64 v = ((u64)seq << 32) | (u64)__float_as_uint(h);
  __hip_atomic_store(p, v, __ATOMIC_RELAXED, __HIP_MEMORY_SCOPE_AGENT);
}

__global__ void
__launch_bounds__(BS)
__attribute__((amdgpu_waves_per_eu(2, 2)))
lstm_fused(
    const float* __restrict__ xin,   // [T][9]
    const float* __restrict__ wih0,  // [4H][9]
    const float* __restrict__ whh0,  // [4H][H]
    const float* __restrict__ bih0, const float* __restrict__ bhh0,
    const float* __restrict__ wih1,  // [4H][H]
    const float* __restrict__ whh1,  // [4H][H]
    const float* __restrict__ bih1, const float* __restrict__ bhh1,
    const float* __restrict__ wlin, const float* __restrict__ blin,
    float* __restrict__ out,
    u64* __restrict__ pub1, u64* __restrict__ pub2)   // [4][HDIM] each
{
  const int b   = blockIdx.x;
  const int tid = threadIdx.x;
  const int wv  = tid >> 6;
  const int ln  = tid & 63;
  const bool isL0 = (wv < 4);
  const int unit = 4 * b + (wv & 3);       // hidden unit this wave owns

  __shared__ __align__(16) float hA[HDIM]; // h1 of the needed step
  __shared__ __align__(16) float hB[HDIM]; // h2 of the needed step
  __shared__ float red8[8];

  // ---- weights -> registers (pinned) -------------------------------------
  // lane ln holds k-chunks k = 4*ln + 256*j (j=0..3) of each gate row.
  float4 wrr[4][4];                         // L0: w_hh0 rows | L1: w_hh1 rows
  {
    const float* WR = isL0 ? whh0 : whh1;
    #pragma unroll
    for (int g = 0; g < 4; ++g)
      #pragma unroll
      for (int j = 0; j < 4; ++j) {
        wrr[g][j] = *reinterpret_cast<const float4*>(
            WR + (size_t)(g * HDIM + unit) * HDIM + 4 * ln + 256 * j);
        pin4(wrr[g][j]);
      }
  }
  float4 wii[4][4];                         // L1 only: w_ih1 rows
  if (!isL0) {
    #pragma unroll
    for (int g = 0; g < 4; ++g)
      #pragma unroll
      for (int j = 0; j < 4; ++j) {
        wii[g][j] = *reinterpret_cast<const float4*>(
            wih1 + (size_t)(g * HDIM + unit) * HDIM + 4 * ln + 256 * j);
        pin4(wii[g][j]);
      }
  }
  float wxr[4][9];                          // L0 only: w_ih0 rows
  if (isL0) {
    #pragma unroll
    for (int g = 0; g < 4; ++g) {
      #pragma unroll
      for (int k = 0; k < 9; ++k)
        wxr[g][k] = wih0[(size_t)(g * HDIM + unit) * 9 + k];
      asm volatile("" : "+v"(wxr[g][0]), "+v"(wxr[g][1]), "+v"(wxr[g][2]),
                        "+v"(wxr[g][3]), "+v"(wxr[g][4]), "+v"(wxr[g][5]),
                        "+v"(wxr[g][6]), "+v"(wxr[g][7]), "+v"(wxr[g][8]));
    }
  }
  float bias[4];
  #pragma unroll
  for (int g = 0; g < 4; ++g)
    bias[g] = isL0 ? (bih0[g * HDIM + unit] + bhh0[g * HDIM + unit])
                   : (bih1[g * HDIM + unit] + bhh1[g * HDIM + unit]);
  asm volatile("" : "+v"(bias[0]), "+v"(bias[1]), "+v"(bias[2]), "+v"(bias[3]));

  float c = 0.0f;                           // cell state (replicated per lane)

  // ======================== round loop ====================================
  for (int r = 0; r <= TSTEPS; ++r) {
    // x(r) for L0 waves — independent of polls, issue early.
    float xr[9];
    if (isL0 && r < TSTEPS) {
      #pragma unroll
      for (int k = 0; k < 9; ++k) xr[k] = xin[r * 9 + k];
    }

    // ---- poll phase: every thread fetches 2 units of each stream --------
    const int i2 = tid * 2;
    if (r >= 1) {                            // need h1[r-1], seq = r
      const u64* s1 = pub1 + (size_t)((r - 1) & RINGM) * HDIM;
      u64 va = pollslot(s1 + i2, (u32)r);
      u64 vb = pollslot(s1 + i2 + 1, (u32)r);
      hA[i2]     = __uint_as_float((u32)va);
      hA[i2 + 1] = __uint_as_float((u32)vb);
    } else {
      hA[i2] = 0.0f; hA[i2 + 1] = 0.0f;
    }
    if (r >= 2) {                            // need h2[r-2], seq = r-1
      const u64* s2 = pub2 + (size_t)((r - 2) & RINGM) * HDIM;
      u64 va = pollslot(s2 + i2, (u32)(r - 1));
      u64 vb = pollslot(s2 + i2 + 1, (u32)(r - 1));
      hB[i2]     = __uint_as_float((u32)va);
      hB[i2 + 1] = __uint_as_float((u32)vb);
    } else {
      hB[i2] = 0.0f; hB[i2 + 1] = 0.0f;
    }
    __syncthreads();                         // LDS staged for all waves

    // ---- compute phase --------------------------------------------------
    if (isL0) {
      if (r < TSTEPS) {
        float a0 = 0, a1 = 0, a2 = 0, a3 = 0;
        #pragma unroll
        for (int j = 0; j < 4; ++j) {
          float4 h4 = reinterpret_cast<const float4*>(hA)[ln + (j << 6)];
          a0 += dot4(wrr[0][j], h4); a1 += dot4(wrr[1][j], h4);
          a2 += dot4(wrr[2][j], h4); a3 += dot4(wrr[3][j], h4);
        }
        #pragma unroll
        for (int d = 1; d < 64; d <<= 1) {
          a0 += __shfl_xor(a0, d); a1 += __shfl_xor(a1, d);
          a2 += __shfl_xor(a2, d); a3 += __shfl_xor(a3, d);
        }
        float g0 = a0 + bias[0], g1 = a1 + bias[1];
        float g2 = a2 + bias[2], g3 = a3 + bias[3];
        #pragma unroll
        for (int k = 0; k < 9; ++k) {
          g0 += wxr[0][k] * xr[k]; g1 += wxr[1][k] * xr[k];
          g2 += wxr[2][k] * xr[k]; g3 += wxr[3][k] * xr[k];
        }
        float gi = sigm(g0), gf = sigm(g1), gg = tanh_(g2), go = sigm(g3);
        c = gf * c + gi * gg;
        float h = go * tanh_(c);
        if (ln == 0)
          publish(pub1 + (size_t)(r & RINGM) * HDIM + unit, (u32)(r + 1), h);
      }
    } else {
      if (r >= 1) {                          // L1 step s = r-1
        float a0 = 0, a1 = 0, a2 = 0, a3 = 0;
        #pragma unroll
        for (int j = 0; j < 4; ++j) {
          float4 ha = reinterpret_cast<const float4*>(hA)[ln + (j << 6)];
          float4 hb = reinterpret_cast<const float4*>(hB)[ln + (j << 6)];
          a0 += dot4(wii[0][j], ha) + dot4(wrr[0][j], hb);
          a1 += dot4(wii[1][j], ha) + dot4(wrr[1][j], hb);
          a2 += dot4(wii[2][j], ha) + dot4(wrr[2][j], hb);
          a3 += dot4(wii[3][j], ha) + dot4(wrr[3][j], hb);
        }
        #pragma unroll
        for (int d = 1; d < 64; d <<= 1) {
          a0 += __shfl_xor(a0, d); a1 += __shfl_xor(a1, d);
          a2 += __shfl_xor(a2, d); a3 += __shfl_xor(a3, d);
        }
        float g0 = a0 + bias[0], g1 = a1 + bias[1];
        float g2 = a2 + bias[2], g3 = a3 + bias[3];
        float gi = sigm(g0), gf = sigm(g1), gg = tanh_(g2), go = sigm(g3);
        c = gf * c + gi * gg;
        float h = go * tanh_(c);
        if (ln == 0)
          publish(pub2 + (size_t)((r - 1) & RINGM) * HDIM + unit, (u32)r, h);
      }
    }
    __syncthreads();                         // hA/hB reads done before re-stage
  }

  // ---- final Linear(h2[T-1]) by block 0 ----------------------------------
  if (b == 0) {
    const u64* s2 = pub2 + (size_t)((TSTEPS - 1) & RINGM) * HDIM;
    const int i2 = tid * 2;
    u64 va = pollslot(s2 + i2, (u32)TSTEPS);
    u64 vb = pollslot(s2 + i2 + 1, (u32)TSTEPS);
    float p = __uint_as_float((u32)va) * wlin[i2]
            + __uint_as_float((u32)vb) * wlin[i2 + 1];
    #pragma unroll
    for (int d = 1; d < 64; d <<= 1) p += __shfl_xor(p, d);
    if (ln == 0) red8[wv] = p;
    __syncthreads();
    if (tid == 0) {
      float s = blin[0];
      #pragma unroll
      for (int w = 0; w < 8; ++w) s += red8[w];
      out[0] = s;
    }
  }
}

extern "C" void kernel_launch(void* const* d_in, const int* in_sizes, int n_in,
                              void* d_out, int out_size, void* d_ws, size_t ws_size,
                              hipStream_t stream)
{
  const float* xin  = (const float*)d_in[0];
  const float* wih0 = (const float*)d_in[1];
  const float* whh0 = (const float*)d_in[2];
  const float* bih0 = (const float*)d_in[3];
  const float* bhh0 = (const float*)d_in[4];
  const float* wih1 = (const float*)d_in[5];
  const float* whh1 = (const float*)d_in[6];
  const float* bih1 = (const float*)d_in[7];
  const float* bhh1 = (const float*)d_in[8];
  const float* wlin = (const float*)d_in[9];
  const float* blin = (const float*)d_in[10];
  float* out = (float*)d_out;

  // Ring mailboxes in ws: pub1[4][1024] u64, pub2[4][1024] u64 = 64 KB total.
  u64* pub1 = (u64*)d_ws;
  u64* pub2 = pub1 + 4 * HDIM;

  void* args[] = { &xin, &wih0, &whh0, &bih0, &bhh0,
                   &wih1, &whh1, &bih1, &bhh1, &wlin, &blin,
                   &out, &pub1, &pub2 };
  hipLaunchCooperativeKernel(reinterpret_cast<void*>(&lstm_fused),
                             dim3(NBLK), dim3(BS), args, 0, stream);
}